// Round 6
// baseline (169.646 us; speedup 1.0000x reference)
//
#include <hip/hip_runtime.h>

typedef _Float16 half8  __attribute__((ext_vector_type(8)));
typedef float    f32x4  __attribute__((ext_vector_type(4)));
typedef float    f32x2  __attribute__((ext_vector_type(2)));
typedef unsigned int u32;

#define QLEN  512
#define NS    64
#define LS    128
#define EDIM  256

// barrier that does NOT drain vmcnt: LDS writes visible, global prefetch stays in flight
__device__ __forceinline__ void block_sync_lds() {
    asm volatile("s_waitcnt lgkmcnt(0)" ::: "memory");
    __builtin_amdgcn_s_barrier();
    asm volatile("" ::: "memory");
}

// ---- K staging: chunk = 32 l x 256 e fp16 (16 KB), double-buffered ----
#define KLOAD(dst, lt) do {                                                   \
  _Pragma("unroll") for (int it = 0; it < 4; ++it) {                          \
    int f = it * 2048 + tid * 8; int r = f >> 8; int e0 = f & 255;            \
    const float* src = kbase + (size_t)((lt) * 32 + r) * EDIM + e0;           \
    dst[2*it]   = *(const f32x4*)src;                                         \
    dst[2*it+1] = *(const f32x4*)(src + 4); } } while (0)

#define KSTORE(sv, bi) do {                                                   \
  _Pragma("unroll") for (int it = 0; it < 4; ++it) {                          \
    int f = it * 2048 + tid * 8; int r = f >> 8; int e0 = f & 255;            \
    f32x4 a = sv[2*it], d = sv[2*it+1]; half8 h;                              \
    h[0]=(_Float16)a[0]; h[1]=(_Float16)a[1]; h[2]=(_Float16)a[2]; h[3]=(_Float16)a[3]; \
    h[4]=(_Float16)d[0]; h[5]=(_Float16)d[1]; h[6]=(_Float16)d[2]; h[7]=(_Float16)d[3]; \
    *(half8*)(kvbuf + (bi) * 16384 + r * 512 + ((e0 * 2) ^ ((r & 7) << 4))) = h; } } while (0)

// ---- V staging: chunk = V^T [256 e][32 l] fp16 (16 KB), rows 64 B, ----
// ---- buffer (lt&1): byte = (lt&1)*16384 + e*64 + ((2*l_local) ^ (((e>>1)&3)<<4)) ----
#define VLOAD(lt) do {                                                        \
  _Pragma("unroll") for (int jj = 0; jj < 2; ++jj)                            \
  _Pragma("unroll") for (int j = 0; j < 8; ++j) {                             \
    int l = (lt) * 32 + vlh * 16 + jj * 8 + j;                                \
    vr[jj*8+j] = *(const f32x2*)(vbase + (size_t)l * EDIM + 2 * vp); } } while (0)

#define VSTORE(lt) do {                                                       \
  _Pragma("unroll") for (int jj = 0; jj < 2; ++jj) {                          \
    half8 h0, h1;                                                             \
    _Pragma("unroll") for (int j = 0; j < 8; ++j) {                           \
      h0[j] = (_Float16)vr[jj*8+j][0]; h1[j] = (_Float16)vr[jj*8+j][1]; }     \
    int l0 = (vlh * 16 + jj * 8) * 2;                                         \
    int sw = (vp & 3) << 4;                                                   \
    unsigned char* vb = kvbuf + ((lt) & 1) * 16384;                           \
    *(half8*)(vb + (2*vp    ) * 64 + (l0 ^ sw)) = h0;                         \
    *(half8*)(vb + (2*vp + 1) * 64 + (l0 ^ sw)) = h1; } } while (0)

// ---- PV: A = V^T frag (LDS), B = P^T frag (exchanged in-register) ----
#define PV(lt) do {                                                           \
  u32 zx = sel2 ? pk0[2*(lt)+1] : pk0[2*(lt)];                                \
  u32 zy = sel2 ? pk1[2*(lt)+1] : pk1[2*(lt)];                                \
  u32 wx = sel2 ? pk0[2*(lt)]   : pk0[2*(lt)+1];                              \
  u32 wy = sel2 ? pk1[2*(lt)]   : pk1[2*(lt)+1];                              \
  u32 az0 = (u32)__shfl((int)zx, s0, 64), az1 = (u32)__shfl((int)zy, s0, 64); \
  u32 aw0 = (u32)__shfl((int)wx, s0, 64), aw1 = (u32)__shfl((int)wy, s0, 64); \
  u32 bz0 = (u32)__shfl((int)zx, s1, 64), bz1 = (u32)__shfl((int)zy, s1, 64); \
  u32 bw0 = (u32)__shfl((int)wx, s1, 64), bw1 = (u32)__shfl((int)wy, s1, 64); \
  union { u32 u[4]; half8 h; } pf;                                            \
  pf.u[0] = useZ ? az0 : aw0;  pf.u[1] = useZ ? az1 : aw1;                    \
  pf.u[2] = useZ ? bz0 : bw0;  pf.u[3] = useZ ? bz1 : bw1;                    \
  const unsigned char* vb = kvbuf + ((lt) & 1) * 16384;                       \
  _Pragma("unroll") for (int et = 0; et < 16; ++et) {                         \
    int e = et * 16 + c;                                                      \
    half8 vf = *(const half8*)(vb + e * 64 + ((g * 16) ^ (((e >> 1) & 3) << 4))); \
    oacc[et] = __builtin_amdgcn_mfma_f32_16x16x32_f16(vf, pf.h, oacc[et], 0, 0, 0); } } while (0)

__global__ __launch_bounds__(256, 3)
void DotAttn_20083267076209_kernel(const float* __restrict__ qg,
                                   const float* __restrict__ kg,
                                   const float* __restrict__ vg,
                                   const int*   __restrict__ maskg,
                                   float*       __restrict__ outg)
{
    // union: K double-buffer 2x16KB  /  V^T chunk buffers 2x16KB (byte-disjoint)
    __shared__ __align__(16) unsigned char kvbuf[32768];

    const int tid  = threadIdx.x;
    const int lane = tid & 63;
    const int c    = lane & 15;
    const int g    = lane >> 4;
    const int vp   = tid & 127;   // e-pair index for V staging
    const int vlh  = tid >> 7;    // l-half within a 32-l chunk

    const bool sel2 = (g >= 2);
    const bool useZ = (g == 0) || (g == 3);
    const int  s0   = c + ((g & 1) << 5);
    const int  s1   = s0 + 16;
    const int  w    = tid >> 6;

    // XCD-bijective decode: all 8 qt-sharers of (b,s) on the same XCD
    const int bid = blockIdx.x;
    const int xcd = bid & 7;
    const int qt  = (bid >> 3) & 7;
    const int b   = (bid >> 6) & 7;
    const int s   = (bid >> 9) * 8 + xcd;

    const float* kbase = kg + (size_t)(b * NS + s) * LS * EDIM;
    const float* vbase = vg + (size_t)(b * NS + s) * LS * EDIM;
    const float* qbase = qg + ((size_t)b * QLEN + (size_t)qt * 64 + (size_t)w * 16) * EDIM;

    // mask ballots: bit l of m0 (l<64) / m1 (l>=64) = keep(l)
    const int* mb = maskg + (b * NS + s) * LS;
    unsigned long long m0 = __ballot(mb[lane] != 0);
    unsigned long long m1 = __ballot(mb[64 + lane] != 0);

    // Q frags (B-operand): lane (c,g) holds Q[q=c][e = ks*32 + g*8 + j]
    half8 qf[8];
#pragma unroll
    for (int ks = 0; ks < 8; ++ks) {
        const float* p = qbase + (size_t)c * EDIM + ks * 32 + g * 8;
        f32x4 a = *(const f32x4*)p;
        f32x4 d = *(const f32x4*)(p + 4);
        half8 h;
        h[0]=(_Float16)a[0]; h[1]=(_Float16)a[1]; h[2]=(_Float16)a[2]; h[3]=(_Float16)a[3];
        h[4]=(_Float16)d[0]; h[5]=(_Float16)d[1]; h[6]=(_Float16)d[2]; h[7]=(_Float16)d[3];
        qf[ks] = h;
    }

    // ---- S^T = K Q^T : sacc[t][r] = S^T[l = t*16 + 4g + r][q = c] ----
    f32x4 kr[8];
    f32x2 vr[16];
    KLOAD(kr, 0);

    f32x4 sacc[8];
#pragma unroll
    for (int t = 0; t < 8; ++t) sacc[t] = (f32x4){0.f, 0.f, 0.f, 0.f};

#pragma unroll
    for (int lt = 0; lt < 4; ++lt) {
        KSTORE(kr, lt & 1);
        if (lt < 3) KLOAD(kr, lt + 1);
        else        VLOAD(0);                 // V chunk0 prefetch, survives the barrier
        block_sync_lds();
        const unsigned char* kb = kvbuf + (lt & 1) * 16384;
#pragma unroll
        for (int lb = 0; lb < 2; ++lb) {
            int row  = lb * 16 + c;
            int base = row * 512;
            int sw   = (c & 7) << 4;
#pragma unroll
            for (int ks = 0; ks < 8; ++ks) {
                half8 kf = *(const half8*)(kb + base + ((ks * 64 + g * 16) ^ sw));
                sacc[lt * 2 + lb] =
                    __builtin_amdgcn_mfma_f32_16x16x32_f16(kf, qf[ks], sacc[lt * 2 + lb], 0, 0, 0);
            }
        }
    }

    // ---- mask (per-lane l = t*16 + 4g + r) ----
#pragma unroll
    for (int t = 0; t < 8; ++t) {
        unsigned bits = (unsigned)(((t < 4 ? m0 : m1) >> ((t & 3) * 16 + 4 * g)) & 0xFull);
#pragma unroll
        for (int r = 0; r < 4; ++r)
            if (!((bits >> r) & 1)) sacc[t][r] = -1e30f;
    }

    // ---- softmax over l for column q=c: 32 local values + lanes c+16k ----
    {
        float m = sacc[0][0];
#pragma unroll
        for (int t = 0; t < 8; ++t)
#pragma unroll
            for (int r = 0; r < 4; ++r) m = fmaxf(m, sacc[t][r]);
        m = fmaxf(m, __shfl_xor(m, 16, 64));
        m = fmaxf(m, __shfl_xor(m, 32, 64));
        float sum = 0.f;
#pragma unroll
        for (int t = 0; t < 8; ++t)
#pragma unroll
            for (int r = 0; r < 4; ++r) {
                float p = __expf(sacc[t][r] - m);
                sacc[t][r] = p;
                sum += p;
            }
        sum += __shfl_xor(sum, 16, 64);
        sum += __shfl_xor(sum, 32, 64);
        float inv = 1.f / sum;
#pragma unroll
        for (int t = 0; t < 8; ++t)
#pragma unroll
            for (int r = 0; r < 4; ++r) sacc[t][r] *= inv;
    }

    // ---- pack P^T to fp16 pairs: pk0[t] = {r0,r1}, pk1[t] = {r2,r3} ----
    u32 pk0[8], pk1[8];
#pragma unroll
    for (int t = 0; t < 8; ++t) {
        pk0[t] = __builtin_bit_cast(u32, __builtin_amdgcn_cvt_pkrtz(sacc[t][0], sacc[t][1]));
        pk1[t] = __builtin_bit_cast(u32, __builtin_amdgcn_cvt_pkrtz(sacc[t][2], sacc[t][3]));
    }

    // ---- O^T = V^T P^T : strict alternation between disjoint 16 KB regions ----
    f32x4 oacc[16];
#pragma unroll
    for (int et = 0; et < 16; ++et) oacc[et] = (f32x4){0.f, 0.f, 0.f, 0.f};

    // [0,16K) = old K half 0: all waves past the lt=3 barrier are done with it;
    // concurrent lt=3 readers only touch [16K,32K). Safe without a barrier.
    VSTORE(0);
    VLOAD(1);
    block_sync_lds();     // B: chunk0 visible; all waves done with K half 1
    PV(0);                // reads [0,16K)
    VSTORE(1);            // writes [16K,32K) — disjoint from PV(0)
    VLOAD(2);
    block_sync_lds();     // C: chunk1 visible; all waves done PV(0)
    PV(1);                // reads [16K,32K)
    VSTORE(2);            // writes [0,16K) — disjoint from PV(1)
    VLOAD(3);
    block_sync_lds();     // D
    PV(2);                // reads [0,16K)
    VSTORE(3);            // writes [16K,32K)
    block_sync_lds();     // E
    PV(3);

    // ---- epilogue: out[b][q=qt*64+w*16+c][s][e = et*16 + 4g + r] ----
    float* ob = outg + (((size_t)b * QLEN + (size_t)qt * 64 + w * 16 + c) * NS + s) * EDIM + 4 * g;
#pragma unroll
    for (int et = 0; et < 16; ++et)
        *(f32x4*)(ob + et * 16) = oacc[et];
}

extern "C" void kernel_launch(void* const* d_in, const int* in_sizes, int n_in,
                              void* d_out, int out_size, void* d_ws, size_t ws_size,
                              hipStream_t stream) {
    const float* q    = (const float*)d_in[0];
    const float* k    = (const float*)d_in[1];
    const float* v    = (const float*)d_in[2];
    const int*   mask = (const int*)d_in[3];
    float* out = (float*)d_out;
    dim3 grid(4096);
    dim3 block(256);
    hipLaunchKernelGGL(DotAttn_20083267076209_kernel, grid, block, 0, stream,
                       q, k, v, mask, out);
}